// Round 15
// baseline (142.300 us; speedup 1.0000x reference)
//
#include <hip/hip_runtime.h>
#include <hip/hip_bf16.h>

typedef __attribute__((ext_vector_type(8))) short  short8;
typedef __attribute__((ext_vector_type(8))) unsigned short ushort8;
typedef __attribute__((ext_vector_type(4))) unsigned short usv4;
typedef __attribute__((ext_vector_type(4))) float  f32x4;

#define D_DIM 1152
#define O_DIM 256
#define N_TOT 100352
#define XT_H 58
#define XT_ROW (58 * 128)

__device__ __forceinline__ unsigned short f2bf(float f) {
  __hip_bfloat16 h = __float2bfloat16(f);
  return __builtin_bit_cast(unsigned short, h);
}

#define GLOAD_LDS16(g, l)                                              \
  __builtin_amdgcn_global_load_lds(                                    \
      (const __attribute__((address_space(1))) void*)(g),              \
      (__attribute__((address_space(3))) void*)(l), 16, 0, 0)

// ---------------------------------------------------------------------------
// Kernel 1: Wt[o][dn] via LDS-tiled fp32 block-GEMM (proven R4)
// ---------------------------------------------------------------------------
__global__ __launch_bounds__(256) void wt_kernel(
    const float* __restrict__ S1s, const float* __restrict__ U1s,
    const float* __restrict__ U2s, const float* __restrict__ S2s,
    unsigned short* __restrict__ Wt) {
  __shared__ float A_lds[32][64];
  __shared__ float B_lds[32][64];

  const int bo = blockIdx.x & 3;
  const int bd = blockIdx.x >> 2;
  const int o0  = bo << 6;
  const int dn0 = bd << 6;
  const int rr  = dn0 >> 7;
  const int c0  = dn0 & 127;

  const int tid = threadIdx.x;
  const int ty = tid >> 4, tx = tid & 15;

  float acc[4][4] = {};

  for (int kc = 0; kc < 15; ++kc) {
#pragma unroll
    for (int e = 0; e < 8; ++e) {
      const int li = e * 256 + tid;
      const int kk = li >> 6;
      const int xx = li & 63;
      const int k  = kc * 32 + kk;
      float av, bv;
      if (k < 48) {
        av = U1s[k * O_DIM + o0 + xx];
        const int d_old = (c0 + xx) * 9 + rr;
        bv = S1s[(size_t)((k >> 3) * D_DIM + d_old) * 8 + (k & 7)];
      } else {
        const int kq = k - 48;
        av = S2s[(size_t)kq * O_DIM + o0 + xx];
        const int d_old = (c0 + xx) * 9 + rr;
        bv = U2s[(size_t)kq * D_DIM + d_old];
      }
      A_lds[kk][xx] = av;
      B_lds[kk][xx] = bv;
    }
    __syncthreads();
#pragma unroll
    for (int kk = 0; kk < 32; ++kk) {
      f32x4 a = *(const f32x4*)&A_lds[kk][ty << 2];
      f32x4 b = *(const f32x4*)&B_lds[kk][tx << 2];
#pragma unroll
      for (int i = 0; i < 4; ++i)
#pragma unroll
        for (int j = 0; j < 4; ++j)
          acc[i][j] += a[i] * b[j];
    }
    __syncthreads();
  }

#pragma unroll
  for (int i = 0; i < 4; ++i) {
    usv4 v;
#pragma unroll
    for (int j = 0; j < 4; ++j) v[j] = f2bf(acc[i][j] * (1.0f / 6.0f));
    *(usv4*)(Wt + (size_t)(o0 + (ty << 2) + i) * D_DIM + dn0 + (tx << 2)) = v;
  }
}

// ---------------------------------------------------------------------------
// Kernel 2: pad+transpose x[B,C,H,W] fp32 -> x_t[b][ih][iw][c] bf16 (proven R4)
// ---------------------------------------------------------------------------
__global__ __launch_bounds__(256) void pad_kernel(const float* __restrict__ x,
                                                  unsigned short* __restrict__ xt) {
  int blk = blockIdx.x;
  int b = blk / XT_H, ih = blk - b * XT_H;
  unsigned short* dst = xt + (size_t)blk * XT_ROW;
  int tid = threadIdx.x;

  if (ih == 0 || ih == XT_H - 1) {
    ushort8 z;
#pragma unroll
    for (int q = 0; q < 8; ++q) z[q] = 0;
    for (int i = tid; i < XT_ROW / 8; i += 256) ((ushort8*)dst)[i] = z;
    return;
  }

  __shared__ unsigned short lds[128 * 58];
  int h = ih - 1;
  const float* xb = x + (size_t)b * 128 * 3136 + (size_t)h * 56;
#pragma unroll 4
  for (int r = 0; r < 28; ++r) {
    int idx = r * 256 + tid;
    int c = idx / 56, w2 = idx - c * 56;
    lds[c * 58 + w2] = f2bf(xb[(size_t)c * 3136 + w2]);
  }
  __syncthreads();
#pragma unroll 4
  for (int r = 0; r < 29; ++r) {
    int idx = r * 256 + tid;
    int iw = idx >> 7, c = idx & 127;
    unsigned short v = 0;
    if (iw >= 1 && iw <= 56) v = lds[c * 58 + (iw - 1)];
    dst[idx] = v;
  }
}

// ---------------------------------------------------------------------------
// Kernel 3: implicit-im2col GEMM — BARRIER-FREE per-wave pipelines.
// Every barriered variant (R4-R14) sat at MfmaUtil 20-25%: workgroup
// barriers propagate each wave's staging latency to all waves, every phase.
// Here each wave owns a PRIVATE 2-slot LDS ping-pong (12KB/slot) and stages
// its own operands with global_load_lds; vmcnt orders its own writes vs its
// own ds_reads -> NO __syncthreads in the whole kernel. Slot reuse is safe
// by program order (own ds_reads -> own MFMAs -> own restage).
// Wave-tile 128o x 64n (acc[8][4]); 4 waves/block share the o-half and take
// consecutive n-64 tiles, so their A-loads are identical addresses -> L1
// absorbs the 4x A duplication (A slice 8KB << 32KB L1). L2 demand/CU ~=
// 24KB per ~650cyc phase = 37B/cyc < 56B/cyc budget.
// Per phase s: issue 12 gloads (slice s+1 -> slot (s+1)&1) -> 12 ds_read_b128
// (slice s) -> 32 MFMA (620cyc, covers staging latency) -> vmcnt(0) (own 12
// loads, ~free) -> flip. 64B-row swizzle (R14-verified, 0 conflicts):
// stored granule = g ^ ((row>>1)&3), pre-swizzled global source.
// ---------------------------------------------------------------------------
__device__ __forceinline__ constexpr int KOFS(int s) {
  // xt element offset for K-slice s (32 ch): rr = s>>2 (kh*3+kw), c0=(s&3)*32
  int rr = s >> 2;
  return ((rr / 3) * 58 + (rr % 3)) * 128 + (s & 3) * 32;
}

// stage slice s_ into this wave's slot ((s_)&1): A 8 gloads + B 4 gloads
#define STAGE_S(s_) do {                                                       \
  unsigned short* _d = smem + wbe + ((s_) & 1) * 6144 + (lane << 3);           \
  _Pragma("unroll")                                                            \
  for (int c = 0; c < 8; ++c)                                                  \
    GLOAD_LDS16(pA[c] + (s_) * 32, _d + c * 512);                              \
  _Pragma("unroll")                                                            \
  for (int c = 0; c < 4; ++c)                                                  \
    GLOAD_LDS16(pB[c] + KOFS(s_), _d + 4096 + c * 512);                        \
} while (0)

// fragment reads: 64B rows; byte = row*64 + ((G ^ ((row>>1)&3))<<4), G=lane>>4
#define AFRAG(q_, row_)                                                        \
  (*(const short8*)((const char*)smem + wbb + (q_) * 12288 + (row_) * 64 +    \
      (((lane >> 4) ^ (((row_) >> 1) & 3)) << 4)))
#define BFRAG(q_, row_)                                                        \
  (*(const short8*)((const char*)smem + wbb + (q_) * 12288 + 8192 +           \
      (row_) * 64 + (((lane >> 4) ^ (((row_) >> 1) & 3)) << 4)))

__global__ __launch_bounds__(256, 1) void gemm_kernel(
    const unsigned short* __restrict__ Wt, const unsigned short* __restrict__ xt,
    const float* __restrict__ bias, float* __restrict__ out) {
  __shared__ __align__(1024) unsigned short smem[49152];  // 96 KiB (4 x 24KB)

  // XCD swizzle (784 % 8 == 0): 98 consecutive lids per XCD.
  const int bid   = blockIdx.x;
  const int lid   = (bid & 7) * 98 + (bid >> 3);
  const int ntile = lid >> 1;        // 0..391 (256-wide n tiles)
  const int ohalf = lid & 1;
  const int obase = ohalf << 7;

  const int tid  = threadIdx.x;
  const int lane = tid & 63;
  const int w    = tid >> 6;
  const int n_w  = (ntile << 8) + (w << 6);   // this wave's n base (64 wide)
  const int la15 = lane & 15;

  const int wbe = w * 12288;   // wave LDS base (elements)
  const int wbb = w * 24576;   // wave LDS base (bytes)

  // staging sources: gload chunk covers 16 rows x 64B; lane -> row lane>>2,
  // stored granule lane&3; source granule = (lane&3) ^ ((row>>1)&3)
  //  = (lane&3) ^ ((lane>>3)&3)  (chunk base is multiple of 16 rows).
  const int srow = lane >> 2;
  const int sg   = (lane & 3) ^ ((lane >> 3) & 3);
  const unsigned short* pA[8];
  const unsigned short* pB[4];
#pragma unroll
  for (int c = 0; c < 8; ++c)
    pA[c] = Wt + (size_t)(obase + c * 16 + srow) * D_DIM + sg * 8;
#pragma unroll
  for (int c = 0; c < 4; ++c) {
    const int n_g = n_w + c * 16 + srow;
    const int b   = n_g / 3136;
    const int s   = n_g - b * 3136;
    const int oh  = s / 56, ow = s - oh * 56;
    pB[c] = xt + (((size_t)b * XT_H + oh) * XT_H + ow) * 128 + sg * 8;
  }

  f32x4 acc[8][4] = {};

  // ---- prologue: stage slice 0 into slot 0 (own loads only) ----
  STAGE_S(0);
  asm volatile("s_waitcnt vmcnt(0)" ::: "memory");

#pragma unroll
  for (int s = 0; s < 36; ++s) {
    const int q = s & 1;

    // issue next slice's staging first (hides under this slice's MFMAs)
    if (s + 1 < 36) STAGE_S(s + 1);

    // fragment reads for slice s (compiler inserts lgkmcnt before MFMA use)
    short8 afr[8], bfr[4];
#pragma unroll
    for (int mi = 0; mi < 8; ++mi)
      afr[mi] = AFRAG(q, mi * 16 + la15);
#pragma unroll
    for (int ni = 0; ni < 4; ++ni)
      bfr[ni] = BFRAG(q, ni * 16 + la15);

    __builtin_amdgcn_s_setprio(1);
#pragma unroll
    for (int mi = 0; mi < 8; ++mi)
#pragma unroll
      for (int ni = 0; ni < 4; ++ni)
        acc[mi][ni] = __builtin_amdgcn_mfma_f32_16x16x32_bf16(
            afr[mi], bfr[ni], acc[mi][ni], 0, 0, 0);
    __builtin_amdgcn_s_setprio(0);

    // own 12 loads (issued ~620cyc ago) -> next slice's slot is ready
    if (s + 1 < 36) asm volatile("s_waitcnt vmcnt(0)" ::: "memory");
  }

  // ---- epilogue: D row = o (obase + mi*16 + (lane>>4)*4 + r), col = n ----
  const int lr = (lane >> 4) << 2;
#pragma unroll
  for (int ni = 0; ni < 4; ++ni) {
    const int ng = n_w + ni * 16 + la15;
    const int b  = ng / 3136;
    const int s  = ng - b * 3136;
    float* op = out + (size_t)b * (O_DIM * 3136) + s;
#pragma unroll
    for (int mi = 0; mi < 8; ++mi) {
      const int og = obase + mi * 16 + lr;
#pragma unroll
      for (int r = 0; r < 4; ++r)
        op[(size_t)(og + r) * 3136] = acc[mi][ni][r] + 2.0f * bias[og + r];
    }
  }
}

// ---------------------------------------------------------------------------
extern "C" void kernel_launch(void* const* d_in, const int* in_sizes, int n_in,
                              void* d_out, int out_size, void* d_ws, size_t ws_size,
                              hipStream_t stream) {
  const float* x    = (const float*)d_in[0];
  const float* S1s  = (const float*)d_in[1];
  const float* U1s  = (const float*)d_in[2];
  const float* U2s  = (const float*)d_in[3];
  const float* S2s  = (const float*)d_in[4];
  const float* bias = (const float*)d_in[5];
  float* out = (float*)d_out;
  (void)ws_size;

  unsigned short* xt = (unsigned short*)d_ws;
  unsigned short* Wt = (unsigned short*)((char*)d_ws + (size_t)32 * XT_H * XT_ROW * 2);

  pad_kernel<<<dim3(32 * XT_H), dim3(256), 0, stream>>>(x, xt);
  wt_kernel<<<dim3(72), dim3(256), 0, stream>>>(S1s, U1s, U2s, S2s, Wt);
  gemm_kernel<<<dim3(784), dim3(256), 0, stream>>>(Wt, xt, bias, out);
}

// Round 16
// 124.104 us; speedup vs baseline: 1.1466x; 1.1466x over previous
//
#include <hip/hip_runtime.h>
#include <hip/hip_bf16.h>

typedef __attribute__((ext_vector_type(8))) short  short8;
typedef __attribute__((ext_vector_type(8))) unsigned short ushort8;
typedef __attribute__((ext_vector_type(4))) unsigned short usv4;
typedef __attribute__((ext_vector_type(4))) float  f32x4;

#define D_DIM 1152
#define O_DIM 256
#define N_TOT 100352
#define XT_H 58
#define XT_ROW (58 * 128)

__device__ __forceinline__ unsigned short f2bf(float f) {
  __hip_bfloat16 h = __float2bfloat16(f);
  return __builtin_bit_cast(unsigned short, h);
}

#define GLOAD_LDS16(g, l)                                              \
  __builtin_amdgcn_global_load_lds(                                    \
      (const __attribute__((address_space(1))) void*)(g),              \
      (__attribute__((address_space(3))) void*)(l), 16, 0, 0)

// ---------------------------------------------------------------------------
// Kernel 1: Wt[o][dn] via LDS-tiled fp32 block-GEMM (proven R4)
// ---------------------------------------------------------------------------
__global__ __launch_bounds__(256) void wt_kernel(
    const float* __restrict__ S1s, const float* __restrict__ U1s,
    const float* __restrict__ U2s, const float* __restrict__ S2s,
    unsigned short* __restrict__ Wt) {
  __shared__ float A_lds[32][64];
  __shared__ float B_lds[32][64];

  const int bo = blockIdx.x & 3;
  const int bd = blockIdx.x >> 2;
  const int o0  = bo << 6;
  const int dn0 = bd << 6;
  const int rr  = dn0 >> 7;
  const int c0  = dn0 & 127;

  const int tid = threadIdx.x;
  const int ty = tid >> 4, tx = tid & 15;

  float acc[4][4] = {};

  for (int kc = 0; kc < 15; ++kc) {
#pragma unroll
    for (int e = 0; e < 8; ++e) {
      const int li = e * 256 + tid;
      const int kk = li >> 6;
      const int xx = li & 63;
      const int k  = kc * 32 + kk;
      float av, bv;
      if (k < 48) {
        av = U1s[k * O_DIM + o0 + xx];
        const int d_old = (c0 + xx) * 9 + rr;
        bv = S1s[(size_t)((k >> 3) * D_DIM + d_old) * 8 + (k & 7)];
      } else {
        const int kq = k - 48;
        av = S2s[(size_t)kq * O_DIM + o0 + xx];
        const int d_old = (c0 + xx) * 9 + rr;
        bv = U2s[(size_t)kq * D_DIM + d_old];
      }
      A_lds[kk][xx] = av;
      B_lds[kk][xx] = bv;
    }
    __syncthreads();
#pragma unroll
    for (int kk = 0; kk < 32; ++kk) {
      f32x4 a = *(const f32x4*)&A_lds[kk][ty << 2];
      f32x4 b = *(const f32x4*)&B_lds[kk][tx << 2];
#pragma unroll
      for (int i = 0; i < 4; ++i)
#pragma unroll
        for (int j = 0; j < 4; ++j)
          acc[i][j] += a[i] * b[j];
    }
    __syncthreads();
  }

#pragma unroll
  for (int i = 0; i < 4; ++i) {
    usv4 v;
#pragma unroll
    for (int j = 0; j < 4; ++j) v[j] = f2bf(acc[i][j] * (1.0f / 6.0f));
    *(usv4*)(Wt + (size_t)(o0 + (ty << 2) + i) * D_DIM + dn0 + (tx << 2)) = v;
  }
}

// ---------------------------------------------------------------------------
// Kernel 2: pad+transpose x[B,C,H,W] fp32 -> x_t[b][ih][iw][c] bf16 (proven R4)
// ---------------------------------------------------------------------------
__global__ __launch_bounds__(256) void pad_kernel(const float* __restrict__ x,
                                                  unsigned short* __restrict__ xt) {
  int blk = blockIdx.x;
  int b = blk / XT_H, ih = blk - b * XT_H;
  unsigned short* dst = xt + (size_t)blk * XT_ROW;
  int tid = threadIdx.x;

  if (ih == 0 || ih == XT_H - 1) {
    ushort8 z;
#pragma unroll
    for (int q = 0; q < 8; ++q) z[q] = 0;
    for (int i = tid; i < XT_ROW / 8; i += 256) ((ushort8*)dst)[i] = z;
    return;
  }

  __shared__ unsigned short lds[128 * 58];
  int h = ih - 1;
  const float* xb = x + (size_t)b * 128 * 3136 + (size_t)h * 56;
#pragma unroll 4
  for (int r = 0; r < 28; ++r) {
    int idx = r * 256 + tid;
    int c = idx / 56, w2 = idx - c * 56;
    lds[c * 58 + w2] = f2bf(xb[(size_t)c * 3136 + w2]);
  }
  __syncthreads();
#pragma unroll 4
  for (int r = 0; r < 29; ++r) {
    int idx = r * 256 + tid;
    int iw = idx >> 7, c = idx & 127;
    unsigned short v = 0;
    if (iw >= 1 && iw <= 56) v = lds[c * 58 + (iw - 1)];
    dst[idx] = v;
  }
}

// ---------------------------------------------------------------------------
// Kernel 3: implicit-im2col GEMM — software-pipelined fragment reads.
// Root cause of R4-R15's 20-25% MfmaUtil: every variant serialized the LDS
// pipe (ds_read ~1130cyc/slice/CU) against the matrix pipe (1242cyc/slice/CU)
// via lgkmcnt(0)+barrier between them. Here, iteration j's ds_reads fetch
// slice j+1's fragments into the ALTERNATE register set while the MFMAs of
// slice j run from the current set -- no dependency, both pipes concurrent.
// BM=256(o) x BN=256(n), 8 waves (2Mx4N), wave-tile 128x64, acc[8][4].
// Ring-4 K=32 slices x [A 256x32 | B 256x32] = 32KB/slot = 128KB LDS.
// Iter j: STAGE(j+3) [4 gloads] -> vmcnt(4) [slices j+1,j+2 landed; never
// drains until tail] -> ds_read frags(j+1) -> 32 MFMA on frags(j) -> barrier.
// Ledger: cross-wave visibility of slice j+1 = predecessor iter's
// vmcnt-before-barrier; slot overwrite (j+5 = j+1 mod 4) is 2 barriers after
// the last read; register consumption (hw lgkm before MFMA at j+1) precedes
// barrier j+1 < overwrite issue at j+2. Dual frag sets indexed j&1 (static
// after full unroll). 64B-row swizzle (R14-verified 0 conflicts):
// granule' = g ^ ((row>>1)&3), pre-swizzled global source, linear LDS dest.
// ---------------------------------------------------------------------------
__device__ __forceinline__ constexpr int KOFS(int s) {
  // xt element offset for K-slice s (32 ch): rr = s>>2 (kh*3+kw), c=(s&3)*32
  int rr = s >> 2;
  return ((rr / 3) * 58 + (rr % 3)) * 128 + (s & 3) * 32;
}

// stage slice s_ into slot (s_&3): A 2 gloads (128 rows each), B 2 gloads
#define STAGE_S(s_) do {                                                       \
  unsigned short* _d = smem + ((s_) & 3) * 16384 + (tid << 3);                 \
  GLOAD_LDS16(pA[0] + (s_) * 32, _d);                                          \
  GLOAD_LDS16(pA[1] + (s_) * 32, _d + 4096);                                   \
  GLOAD_LDS16(pB[0] + KOFS(s_), _d + 8192);                                    \
  GLOAD_LDS16(pB[1] + KOFS(s_), _d + 12288);                                   \
} while (0)

// fragment reads: 64B rows; byte = row*64 + ((G ^ ((row>>1)&3))<<4), G=lane>>4
#define AFRAG(sl_, row_)                                                       \
  (*(const short8*)((const char*)smem + (sl_) * 32768 + (row_) * 64 +        \
      (((lane >> 4) ^ (((row_) >> 1) & 3)) << 4)))
#define BFRAG(sl_, row_)                                                       \
  (*(const short8*)((const char*)smem + (sl_) * 32768 + 16384 + (row_) * 64 + \
      (((lane >> 4) ^ (((row_) >> 1) & 3)) << 4)))

#define READ_FRAGS(set_, sl_) do {                                             \
  _Pragma("unroll")                                                            \
  for (int mi = 0; mi < 8; ++mi)                                               \
    fA[set_][mi] = AFRAG(sl_, (wm << 7) + (mi << 4) + la15);                   \
  _Pragma("unroll")                                                            \
  for (int ni = 0; ni < 4; ++ni)                                               \
    fB[set_][ni] = BFRAG(sl_, (wn << 6) + (ni << 4) + la15);                   \
} while (0)

__global__ __launch_bounds__(512, 1) void gemm_kernel(
    const unsigned short* __restrict__ Wt, const unsigned short* __restrict__ xt,
    const float* __restrict__ bias, float* __restrict__ out) {
  __shared__ __align__(1024) unsigned short smem[65536];  // 128 KiB

  // XCD swizzle (392 % 8 == 0): each XCD gets 49 consecutive n-tiles.
  const int bid   = blockIdx.x;
  const int ntile = (bid & 7) * 49 + (bid >> 3);
  const int n0    = ntile << 8;

  const int tid  = threadIdx.x;
  const int lane = tid & 63;
  const int w    = tid >> 6;
  const int wm   = w >> 2;       // 0..1 (o half: 128 rows)
  const int wn   = w & 3;        // 0..3 (n quarter: 64 rows)
  const int la15 = lane & 15;

  // staging: gload covers 512 thr x 16B = 8KB = 128 rows x 64B.
  // thread t: row (within 128-row group) = t>>2, stored granule = t&3;
  // source granule = (t&3) ^ ((row>>1)&3) = (t&3) ^ ((t>>3)&3).
  const int srow = tid >> 2;                  // 0..127
  const int sg   = (tid & 3) ^ ((tid >> 3) & 3);
  const unsigned short* pA[2];
  const unsigned short* pB[2];
#pragma unroll
  for (int r = 0; r < 2; ++r) {
    pA[r] = Wt + (size_t)(r * 128 + srow) * D_DIM + sg * 8;
    const int n_g = n0 + r * 128 + srow;
    const int b   = n_g / 3136;
    const int s   = n_g - b * 3136;
    const int oh  = s / 56, ow = s - oh * 56;
    pB[r] = xt + (((size_t)b * XT_H + oh) * XT_H + ow) * 128 + sg * 8;
  }

  f32x4 acc[8][4] = {};
  short8 fA[2][8], fB[2][4];

  // ---- prologue: stage slices 0,1,2; slice 0 landed; read frags(0) ----
  STAGE_S(0);
  STAGE_S(1);
  STAGE_S(2);
  asm volatile("s_waitcnt vmcnt(8)" ::: "memory");   // slice 0's 4 landed
  __builtin_amdgcn_s_barrier();
  READ_FRAGS(0, 0);

#pragma unroll
  for (int j = 0; j < 36; ++j) {
    const int cur = j & 1;
    const int nxt = cur ^ 1;

    // ---- stage slice j+3 (slot (j+3)&3, freed 2 barriers ago) ----
    if (j + 3 < 36) STAGE_S(j + 3);

    // ---- counted wait: slices j+1 (and j+2) landed; no drain until tail ----
    if (j <= 32)      asm volatile("s_waitcnt vmcnt(4)" ::: "memory");
    else if (j == 33) asm volatile("s_waitcnt vmcnt(4)" ::: "memory");
    else if (j == 34) asm volatile("s_waitcnt vmcnt(0)" ::: "memory");

    // ---- ds_read frags(j+1) into alternate set (independent of MFMAs) ----
    if (j + 1 < 36) READ_FRAGS(nxt, (j + 1) & 3);

    // ---- MFMA cluster on frags(j): overlaps the ds_reads above ----
    __builtin_amdgcn_s_setprio(1);
#pragma unroll
    for (int mi = 0; mi < 8; ++mi)
#pragma unroll
      for (int ni = 0; ni < 4; ++ni)
        acc[mi][ni] = __builtin_amdgcn_mfma_f32_16x16x32_bf16(
            fA[cur][mi], fB[cur][ni], acc[mi][ni], 0, 0, 0);
    __builtin_amdgcn_s_setprio(0);

    if (j + 1 < 36) __builtin_amdgcn_s_barrier();
  }

  // ---- epilogue: D row = o ((lane>>4)*4+reg), col = n (lane&15) ----
  const int lr = (lane >> 4) << 2;
#pragma unroll
  for (int ni = 0; ni < 4; ++ni) {
    const int ng = n0 + (wn << 6) + (ni << 4) + la15;
    const int b  = ng / 3136;
    const int s  = ng - b * 3136;
    float* op = out + (size_t)b * (O_DIM * 3136) + s;
#pragma unroll
    for (int mi = 0; mi < 8; ++mi) {
      const int og = (wm << 7) + (mi << 4) + lr;
#pragma unroll
      for (int r = 0; r < 4; ++r)
        op[(size_t)(og + r) * 3136] = acc[mi][ni][r] + 2.0f * bias[og + r];
    }
  }
}

// ---------------------------------------------------------------------------
extern "C" void kernel_launch(void* const* d_in, const int* in_sizes, int n_in,
                              void* d_out, int out_size, void* d_ws, size_t ws_size,
                              hipStream_t stream) {
  const float* x    = (const float*)d_in[0];
  const float* S1s  = (const float*)d_in[1];
  const float* U1s  = (const float*)d_in[2];
  const float* U2s  = (const float*)d_in[3];
  const float* S2s  = (const float*)d_in[4];
  const float* bias = (const float*)d_in[5];
  float* out = (float*)d_out;
  (void)ws_size;

  unsigned short* xt = (unsigned short*)d_ws;
  unsigned short* Wt = (unsigned short*)((char*)d_ws + (size_t)32 * XT_H * XT_ROW * 2);

  pad_kernel<<<dim3(32 * XT_H), dim3(256), 0, stream>>>(x, xt);
  wt_kernel<<<dim3(72), dim3(256), 0, stream>>>(S1s, U1s, U2s, S2s, Wt);
  gemm_kernel<<<dim3(392), dim3(512), 0, stream>>>(Wt, xt, bias, out);
}

// Round 17
// 114.604 us; speedup vs baseline: 1.2417x; 1.0829x over previous
//
#include <hip/hip_runtime.h>
#include <hip/hip_bf16.h>

typedef __attribute__((ext_vector_type(8))) short  short8;
typedef __attribute__((ext_vector_type(8))) unsigned short ushort8;
typedef __attribute__((ext_vector_type(4))) unsigned short usv4;
typedef __attribute__((ext_vector_type(4))) float  f32x4;

#define D_DIM 1152
#define O_DIM 256
#define N_TOT 100352
#define XT_H 58
#define XT_ROW (58 * 128)

__device__ __forceinline__ unsigned short f2bf(float f) {
  __hip_bfloat16 h = __float2bfloat16(f);
  return __builtin_bit_cast(unsigned short, h);
}

#define GLOAD_LDS16(g, l)                                              \
  __builtin_amdgcn_global_load_lds(                                    \
      (const __attribute__((address_space(1))) void*)(g),              \
      (__attribute__((address_space(3))) void*)(l), 16, 0, 0)

// ---------------------------------------------------------------------------
// Kernel 1: Wt[o][dn] via LDS-tiled fp32 block-GEMM (proven R4)
// ---------------------------------------------------------------------------
__global__ __launch_bounds__(256) void wt_kernel(
    const float* __restrict__ S1s, const float* __restrict__ U1s,
    const float* __restrict__ U2s, const float* __restrict__ S2s,
    unsigned short* __restrict__ Wt) {
  __shared__ float A_lds[32][64];
  __shared__ float B_lds[32][64];

  const int bo = blockIdx.x & 3;
  const int bd = blockIdx.x >> 2;
  const int o0  = bo << 6;
  const int dn0 = bd << 6;
  const int rr  = dn0 >> 7;
  const int c0  = dn0 & 127;

  const int tid = threadIdx.x;
  const int ty = tid >> 4, tx = tid & 15;

  float acc[4][4] = {};

  for (int kc = 0; kc < 15; ++kc) {
#pragma unroll
    for (int e = 0; e < 8; ++e) {
      const int li = e * 256 + tid;
      const int kk = li >> 6;
      const int xx = li & 63;
      const int k  = kc * 32 + kk;
      float av, bv;
      if (k < 48) {
        av = U1s[k * O_DIM + o0 + xx];
        const int d_old = (c0 + xx) * 9 + rr;
        bv = S1s[(size_t)((k >> 3) * D_DIM + d_old) * 8 + (k & 7)];
      } else {
        const int kq = k - 48;
        av = S2s[(size_t)kq * O_DIM + o0 + xx];
        const int d_old = (c0 + xx) * 9 + rr;
        bv = U2s[(size_t)kq * D_DIM + d_old];
      }
      A_lds[kk][xx] = av;
      B_lds[kk][xx] = bv;
    }
    __syncthreads();
#pragma unroll
    for (int kk = 0; kk < 32; ++kk) {
      f32x4 a = *(const f32x4*)&A_lds[kk][ty << 2];
      f32x4 b = *(const f32x4*)&B_lds[kk][tx << 2];
#pragma unroll
      for (int i = 0; i < 4; ++i)
#pragma unroll
        for (int j = 0; j < 4; ++j)
          acc[i][j] += a[i] * b[j];
    }
    __syncthreads();
  }

#pragma unroll
  for (int i = 0; i < 4; ++i) {
    usv4 v;
#pragma unroll
    for (int j = 0; j < 4; ++j) v[j] = f2bf(acc[i][j] * (1.0f / 6.0f));
    *(usv4*)(Wt + (size_t)(o0 + (ty << 2) + i) * D_DIM + dn0 + (tx << 2)) = v;
  }
}

// ---------------------------------------------------------------------------
// Kernel 2: pad+transpose x[B,C,H,W] fp32 -> x_t[b][ih][iw][c] bf16 (proven R4)
// ---------------------------------------------------------------------------
__global__ __launch_bounds__(256) void pad_kernel(const float* __restrict__ x,
                                                  unsigned short* __restrict__ xt) {
  int blk = blockIdx.x;
  int b = blk / XT_H, ih = blk - b * XT_H;
  unsigned short* dst = xt + (size_t)blk * XT_ROW;
  int tid = threadIdx.x;

  if (ih == 0 || ih == XT_H - 1) {
    ushort8 z;
#pragma unroll
    for (int q = 0; q < 8; ++q) z[q] = 0;
    for (int i = tid; i < XT_ROW / 8; i += 256) ((ushort8*)dst)[i] = z;
    return;
  }

  __shared__ unsigned short lds[128 * 58];
  int h = ih - 1;
  const float* xb = x + (size_t)b * 128 * 3136 + (size_t)h * 56;
#pragma unroll 4
  for (int r = 0; r < 28; ++r) {
    int idx = r * 256 + tid;
    int c = idx / 56, w2 = idx - c * 56;
    lds[c * 58 + w2] = f2bf(xb[(size_t)c * 3136 + w2]);
  }
  __syncthreads();
#pragma unroll 4
  for (int r = 0; r < 29; ++r) {
    int idx = r * 256 + tid;
    int iw = idx >> 7, c = idx & 127;
    unsigned short v = 0;
    if (iw >= 1 && iw <= 56) v = lds[c * 58 + (iw - 1)];
    dst[idx] = v;
  }
}

// ---------------------------------------------------------------------------
// Kernel 3: implicit-im2col GEMM — balanced grid + 2 independent blocks/CU.
// Diagnosis across R4-R16: (1) 392-block grids cap at 77% CU balance; (2) at
// 1 resident block, barrier/drain stalls idle the CU's MFMA pipe with no
// other block to fill (m114's cross-block overlap is m97's actual hiding
// mechanism). Fix: BM=128 x BN=128, grid 1568 (87% balance), 4 waves/block
// (wave-tile 64x64, acc[4][4]), DOUBLE-buffered 2x32KB = 64KB LDS -> TWO
// blocks resident per CU with independent barrier groups.
// Per K-tile: issue STAGE(kt+1 -> buf^1) first (8 gloads), then 16 frag
// ds_reads(kt), then 32 MFMA (~800cyc), then vmcnt(0)-with-slack + ONE
// barrier. Buffer-overwrite safety: frags of kt-1 (from buf^1) completed
// before kt-1's MFMAs (hw lgkmcnt) which precede the barrier we crossed.
// Layout: 128B rows, R7/R11-verified zero-conflict swizzle (granule ^= row&7,
// pre-swizzled global source, linear LDS dest).
// ---------------------------------------------------------------------------
__device__ __forceinline__ constexpr int KOF(int kt) {
  // xt element offset of K-tile kt: (kh*58+kw)*128 + (kt&1)*64
  int rr = kt >> 1;
  return ((rr / 3) * 58 + (rr % 3)) * 128 + (kt & 1) * 64;
}

// stage K-tile kt_ into buffer bf_: 4 A-gloads + 4 B-gloads (4KB each)
#define STAGE(kt_, bf_) do {                                                   \
  _Pragma("unroll")                                                            \
  for (int j = 0; j < 4; ++j) {                                                \
    const int chunk = (w << 2) + j;                                            \
    GLOAD_LDS16(pA[j] + (kt_) * 64,                                            \
                smem + (bf_) * 16384 + (chunk << 9) + sdst);                   \
    GLOAD_LDS16(pB[j] + KOF(kt_),                                              \
                smem + (bf_) * 16384 + 8192 + (chunk << 9) + sdst);            \
  }                                                                            \
} while (0)

// fragment read: 128B rows; granule = (ks*4 + (lane>>4)) ^ (row&7)
#define AFRAG(bf_, row_, ks_)                                                  \
  (*(const short8*)((const char*)smem + (bf_) * 32768 + (row_) * 128 +        \
      (((((ks_) << 2) + (lane >> 4)) ^ ((row_) & 7)) << 4)))
#define BFRAG(bf_, row_, ks_)                                                  \
  (*(const short8*)((const char*)smem + (bf_) * 32768 + 16384 + (row_) * 128 +\
      (((((ks_) << 2) + (lane >> 4)) ^ ((row_) & 7)) << 4)))

__global__ __launch_bounds__(256) void gemm_kernel(
    const unsigned short* __restrict__ Wt, const unsigned short* __restrict__ xt,
    const float* __restrict__ bias, float* __restrict__ out) {
  __shared__ __align__(1024) unsigned short smem[32768];  // 2 x 32KB

  // XCD swizzle (1568 % 8 == 0): pair the 2 o-tiles of each n-tile per XCD.
  const int bid   = blockIdx.x;
  const int lid   = (bid & 7) * 196 + (bid >> 3);
  const int ntile = lid >> 1, otile = lid & 1;
  const int n0 = ntile << 7, o0 = otile << 7;

  const int tid  = threadIdx.x;
  const int w    = tid >> 6;
  const int lane = tid & 63;
  const int wr   = (w >> 1) << 6;   // wave o-offset
  const int wc   = (w & 1) << 6;    // wave n-offset
  const int la15 = lane & 15;

  // linear LDS dest within a chunk (8 rows x 128B): row = lane>>3, gran = lane&7
  const int sdst = ((lane & 7) << 3) + ((lane >> 3) << 6);

  // staging sources (R11-verified): chunk = w*4+j covers rows chunk*8..+7;
  // source granule pre-swizzled = (lane&7) ^ (row&7).
  const unsigned short* pA[4];
  const unsigned short* pB[4];
#pragma unroll
  for (int j = 0; j < 4; ++j) {
    const int chunk = (w << 2) + j;
    const int row   = (chunk << 3) + (lane >> 3);
    const int gs    = (lane & 7) ^ (row & 7);
    pA[j] = Wt + (size_t)(o0 + row) * D_DIM + gs * 8;
    const int n_g = n0 + row;
    const int b   = n_g / 3136;
    const int s   = n_g - b * 3136;
    const int oh  = s / 56, ow = s - oh * 56;
    pB[j] = xt + (((size_t)b * XT_H + oh) * XT_H + ow) * 128 + gs * 8;
  }

  f32x4 acc[4][4] = {};

  // ---- prologue: stage K-tile 0 into buf 0 ----
  STAGE(0, 0);
  asm volatile("s_waitcnt vmcnt(0)" ::: "memory");
  __builtin_amdgcn_s_barrier();

#pragma unroll
  for (int kt = 0; kt < 18; ++kt) {
    const int bf = kt & 1;

    // ---- issue next tile's staging FIRST (hides L2 latency under reads+MFMA)
    if (kt + 1 < 18) STAGE(kt + 1, bf ^ 1);

    // ---- fragment reads for kt ----
    short8 af[4][2], bfr[4][2];
#pragma unroll
    for (int m = 0; m < 4; ++m) {
      af[m][0] = AFRAG(bf, wr + m * 16 + la15, 0);
      af[m][1] = AFRAG(bf, wr + m * 16 + la15, 1);
    }
#pragma unroll
    for (int n = 0; n < 4; ++n) {
      bfr[n][0] = BFRAG(bf, wc + n * 16 + la15, 0);
      bfr[n][1] = BFRAG(bf, wc + n * 16 + la15, 1);
    }

    // ---- MFMA x32 (compiler inserts lgkmcnt before first use) ----
    __builtin_amdgcn_s_setprio(1);
#pragma unroll
    for (int ks = 0; ks < 2; ++ks)
#pragma unroll
      for (int m = 0; m < 4; ++m)
#pragma unroll
        for (int n = 0; n < 4; ++n)
          acc[m][n] = __builtin_amdgcn_mfma_f32_16x16x32_bf16(
              af[m][ks], bfr[n][ks], acc[m][n], 0, 0, 0);
    __builtin_amdgcn_s_setprio(0);

    // ---- drain own stage loads (issued ~800cyc ago -> cheap); barrier ----
    if (kt + 1 < 18) {
      asm volatile("s_waitcnt vmcnt(0)" ::: "memory");
      __builtin_amdgcn_s_barrier();
    }
  }

  // ---- epilogue: D row = o ((lane>>4)*4+reg), col = n (lane&15) ----
  const int lr = (lane >> 4) << 2;
#pragma unroll
  for (int n = 0; n < 4; ++n) {
    const int ng = n0 + wc + n * 16 + la15;
    const int b  = ng / 3136;
    const int s  = ng - b * 3136;
    float* op = out + (size_t)b * (O_DIM * 3136) + s;
#pragma unroll
    for (int m = 0; m < 4; ++m) {
      const int og = o0 + wr + m * 16 + lr;
#pragma unroll
      for (int r = 0; r < 4; ++r)
        op[(size_t)(og + r) * 3136] = acc[m][n][r] + 2.0f * bias[og + r];
    }
  }
}

// ---------------------------------------------------------------------------
extern "C" void kernel_launch(void* const* d_in, const int* in_sizes, int n_in,
                              void* d_out, int out_size, void* d_ws, size_t ws_size,
                              hipStream_t stream) {
  const float* x    = (const float*)d_in[0];
  const float* S1s  = (const float*)d_in[1];
  const float* U1s  = (const float*)d_in[2];
  const float* U2s  = (const float*)d_in[3];
  const float* S2s  = (const float*)d_in[4];
  const float* bias = (const float*)d_in[5];
  float* out = (float*)d_out;
  (void)ws_size;

  unsigned short* xt = (unsigned short*)d_ws;
  unsigned short* Wt = (unsigned short*)((char*)d_ws + (size_t)32 * XT_H * XT_ROW * 2);

  pad_kernel<<<dim3(32 * XT_H), dim3(256), 0, stream>>>(x, xt);
  wt_kernel<<<dim3(72), dim3(256), 0, stream>>>(S1s, U1s, U2s, S2s, Wt);
  gemm_kernel<<<dim3(1568), dim3(256), 0, stream>>>(Wt, xt, bias, out);
}